// Round 1
// baseline (1297.038 us; speedup 1.0000x reference)
//
#include <hip/hip_runtime.h>

#define N_NODES 100000
#define N_EDGES 1600000

// ---------------- degree / norm / coef ----------------

__global__ void deg_kernel(const int* __restrict__ src, const int* __restrict__ dst,
                           float* __restrict__ deg_out, float* __restrict__ deg_in) {
    int i = blockIdx.x * blockDim.x + threadIdx.x;
    int stride = gridDim.x * blockDim.x;
    for (int e = i; e < N_EDGES; e += stride) {
        atomicAdd(&deg_out[src[e]], 1.0f);
        atomicAdd(&deg_in[dst[e]], 1.0f);
    }
}

__global__ void norm_kernel(float* __restrict__ deg_out, float* __restrict__ deg_in) {
    int i = blockIdx.x * blockDim.x + threadIdx.x;
    int stride = gridDim.x * blockDim.x;
    for (int n = i; n < N_NODES; n += stride) {
        deg_out[n] = rsqrtf(fmaxf(deg_out[n], 1.0f));
        deg_in[n]  = rsqrtf(fmaxf(deg_in[n], 1.0f));
    }
}

__global__ void coef_kernel(const int* __restrict__ src, const int* __restrict__ dst,
                            const float* __restrict__ ew,
                            const float* __restrict__ ns, const float* __restrict__ nd,
                            float* __restrict__ coef) {
    int i = blockIdx.x * blockDim.x + threadIdx.x;
    int stride = gridDim.x * blockDim.x;
    for (int e = i; e < N_EDGES; e += stride) {
        coef[e] = ns[src[e]] * ew[e] * nd[dst[e]];
    }
}

// ---------------- dense transform: h = act(x [+b]) @ W ----------------
// One wave per node. Lane l holds x[node*64+l]; broadcast via __shfl.
// W is (64 x DOUT) row-major, staged in LDS.

template <int DOUT, bool BIAS_RELU>
__global__ void matmul_kernel(const float* __restrict__ x, const float* __restrict__ W,
                              const float* __restrict__ bin, float* __restrict__ h) {
    __shared__ float Wl[64 * DOUT];
    int tid = threadIdx.x;
    for (int i = tid; i < 64 * DOUT; i += blockDim.x) Wl[i] = W[i];
    __syncthreads();

    int lane = tid & 63;
    int wid = tid >> 6;                       // wave index in block (block=256 -> 4 waves)
    int wglobal = blockIdx.x * 4 + wid;
    int nwaves = gridDim.x * 4;
    int olane = lane & (DOUT - 1);            // for DOUT=32, upper half mirrors lower

    float bv = 0.0f;
    if (BIAS_RELU) bv = bin[lane];

    for (int n = wglobal; n < N_NODES; n += nwaves) {
        float xv = x[n * 64 + lane];
        if (BIAS_RELU) xv = fmaxf(xv + bv, 0.0f);
        float acc = 0.0f;
#pragma unroll
        for (int k = 0; k < 64; ++k) {
            float xk = __shfl(xv, k);
            acc += xk * Wl[k * DOUT + olane];
        }
        if (lane < DOUT) h[n * DOUT + lane] = acc;
    }
}

// ---------------- edge aggregation: agg[dst] += coef * h[src] ----------------
// D lanes per edge (D = feature dim of h). Coalesced gather, per-element atomic scatter.

template <int D>
__global__ void aggregate_kernel(const int* __restrict__ src, const int* __restrict__ dst,
                                 const float* __restrict__ coef,
                                 const float* __restrict__ h, float* __restrict__ agg) {
    int tid = blockIdx.x * blockDim.x + threadIdx.x;
    int stride = gridDim.x * blockDim.x;
    int lane = tid % D;
    int eidx = tid / D;
    int estride = stride / D;
    for (int e = eidx; e < N_EDGES; e += estride) {
        int s = src[e];
        int d = dst[e];
        float c = coef[e];
        atomicAdd(&agg[d * D + lane], h[s * D + lane] * c);
    }
}

// ---------------- final bias ----------------

__global__ void bias_kernel(const float* __restrict__ agg, const float* __restrict__ bp,
                            float* __restrict__ out) {
    int i = blockIdx.x * blockDim.x + threadIdx.x;
    int stride = gridDim.x * blockDim.x;
    for (int k = i; k < N_NODES * 32; k += stride) {
        out[k] = agg[k] + bp[k & 31];
    }
}

extern "C" void kernel_launch(void* const* d_in, const int* in_sizes, int n_in,
                              void* d_out, int out_size, void* d_ws, size_t ws_size,
                              hipStream_t stream) {
    const float* features = (const float*)d_in[0];
    const float* ew       = (const float*)d_in[1];
    const int*   src      = (const int*)d_in[2];
    const int*   dst      = (const int*)d_in[3];
    const float* W1       = (const float*)d_in[4];
    const float* b1       = (const float*)d_in[5];
    const float* W2       = (const float*)d_in[6];
    const float* b2       = (const float*)d_in[7];
    const float* Wp       = (const float*)d_in[8];
    const float* bp       = (const float*)d_in[9];
    float* out = (float*)d_out;

    float* ws       = (float*)d_ws;
    float* norm_src = ws;                       // N
    float* norm_dst = ws + N_NODES;             // N
    float* coef     = ws + 2 * N_NODES;         // E
    float* h        = coef + N_EDGES;           // N*64
    float* agg      = h + N_NODES * 64;         // N*64

    // degrees -> norms -> per-edge coefficient (norms fully folded into coef)
    hipMemsetAsync(norm_src, 0, 2 * N_NODES * sizeof(float), stream);
    deg_kernel<<<2048, 256, 0, stream>>>(src, dst, norm_src, norm_dst);
    norm_kernel<<<512, 256, 0, stream>>>(norm_src, norm_dst);
    coef_kernel<<<2048, 256, 0, stream>>>(src, dst, ew, norm_src, norm_dst, coef);

    // ---- layer 1: x1 = relu(A*(features@W1) + b1)  (bias+relu deferred to layer-2 load)
    matmul_kernel<64, false><<<1024, 256, 0, stream>>>(features, W1, nullptr, h);
    hipMemsetAsync(agg, 0, N_NODES * 64 * sizeof(float), stream);
    aggregate_kernel<64><<<4096, 256, 0, stream>>>(src, dst, coef, h, agg);

    // ---- layer 2: h2 = relu(agg1+b1) @ W2 ; agg2 = A*h2
    matmul_kernel<64, true><<<1024, 256, 0, stream>>>(agg, W2, b1, h);
    hipMemsetAsync(agg, 0, N_NODES * 64 * sizeof(float), stream);
    aggregate_kernel<64><<<4096, 256, 0, stream>>>(src, dst, coef, h, agg);

    // ---- layer 3: h3 = relu(agg2+b2) @ Wp (64->32) ; agg3 = A*h3 ; out = agg3 + bp
    matmul_kernel<32, true><<<1024, 256, 0, stream>>>(agg, Wp, b2, h);
    hipMemsetAsync(agg, 0, N_NODES * 32 * sizeof(float), stream);
    aggregate_kernel<32><<<4096, 256, 0, stream>>>(src, dst, coef, h, agg);
    bias_kernel<<<2048, 256, 0, stream>>>(agg, bp, out);
}

// Round 2
// 1008.599 us; speedup vs baseline: 1.2860x; 1.2860x over previous
//
#include <hip/hip_runtime.h>

#define N_NODES 100000
#define N_EDGES 1600000
#define SCAN_T 1024

// ---------------- degree counting ----------------

__global__ void deg_kernel(const int* __restrict__ src, const int* __restrict__ dst,
                           float* __restrict__ deg_out, float* __restrict__ deg_in) {
    int i = blockIdx.x * blockDim.x + threadIdx.x;
    int stride = gridDim.x * blockDim.x;
    for (int e = i; e < N_EDGES; e += stride) {
        atomicAdd(&deg_out[src[e]], 1.0f);
        atomicAdd(&deg_in[dst[e]], 1.0f);
    }
}

// single-block exclusive scan of in-degrees -> row_ptr[0..N] and cursor copy
__global__ void scan_kernel(const float* __restrict__ deg_in,
                            int* __restrict__ row_ptr, int* __restrict__ cursor) {
    __shared__ int part[SCAN_T];
    int t = threadIdx.x;
    const int CH = (N_NODES + SCAN_T - 1) / SCAN_T;   // 98
    int base = t * CH;
    int s = 0;
    for (int i = 0; i < CH; ++i) {
        int n = base + i;
        if (n < N_NODES) s += (int)deg_in[n];
    }
    part[t] = s;
    __syncthreads();
    // Hillis-Steele inclusive scan over 1024 partials
    for (int off = 1; off < SCAN_T; off <<= 1) {
        int v = (t >= off) ? part[t - off] : 0;
        __syncthreads();
        part[t] += v;
        __syncthreads();
    }
    int run = (t == 0) ? 0 : part[t - 1];
    for (int i = 0; i < CH; ++i) {
        int n = base + i;
        if (n < N_NODES) {
            row_ptr[n] = run;
            cursor[n] = run;
            run += (int)deg_in[n];
        }
    }
    if (t == SCAN_T - 1) row_ptr[N_NODES] = run;      // == N_EDGES
}

__global__ void norm_kernel(float* __restrict__ deg_out, float* __restrict__ deg_in) {
    int i = blockIdx.x * blockDim.x + threadIdx.x;
    int stride = gridDim.x * blockDim.x;
    for (int n = i; n < N_NODES; n += stride) {
        deg_out[n] = rsqrtf(fmaxf(deg_out[n], 1.0f));
        deg_in[n]  = rsqrtf(fmaxf(deg_in[n], 1.0f));
    }
}

// fill CSR-by-dst: permuted src index + fully-folded per-edge coefficient
__global__ void fill_kernel(const int* __restrict__ src, const int* __restrict__ dst,
                            const float* __restrict__ ew,
                            const float* __restrict__ ns, const float* __restrict__ nd,
                            int* __restrict__ cursor,
                            int* __restrict__ esrc, float* __restrict__ ecoef) {
    int i = blockIdx.x * blockDim.x + threadIdx.x;
    int stride = gridDim.x * blockDim.x;
    for (int e = i; e < N_EDGES; e += stride) {
        int s = src[e];
        int d = dst[e];
        float c = ns[s] * ew[e] * nd[d];
        int p = atomicAdd(&cursor[d], 1);
        esrc[p] = s;
        ecoef[p] = c;
    }
}

// ---------------- dense transform: h = act(x [+b]) @ W ----------------
// One wave per node. Lane l holds x[node*64+l]; broadcast via __shfl.

template <int DOUT, bool BIAS_RELU>
__global__ void matmul_kernel(const float* __restrict__ x, const float* __restrict__ W,
                              const float* __restrict__ bin, float* __restrict__ h) {
    __shared__ float Wl[64 * DOUT];
    int tid = threadIdx.x;
    for (int i = tid; i < 64 * DOUT; i += blockDim.x) Wl[i] = W[i];
    __syncthreads();

    int lane = tid & 63;
    int wid = tid >> 6;
    int wglobal = blockIdx.x * 4 + wid;
    int nwaves = gridDim.x * 4;
    int olane = lane & (DOUT - 1);

    float bv = 0.0f;
    if (BIAS_RELU) bv = bin[lane];

    for (int n = wglobal; n < N_NODES; n += nwaves) {
        float xv = x[n * 64 + lane];
        if (BIAS_RELU) xv = fmaxf(xv + bv, 0.0f);
        float acc = 0.0f;
#pragma unroll
        for (int k = 0; k < 64; ++k) {
            float xk = __shfl(xv, k);
            acc += xk * Wl[k * DOUT + olane];
        }
        if (lane < DOUT) h[n * DOUT + lane] = acc;
    }
}

// ---------------- CSR aggregation: agg[n] = sum_{e in in(n)} coef[e]*h[src[e]] ----------------
// D lanes per node (D=64: wave/node, D=32: half-wave/node). Register accumulate, one write.

template <int D, bool FINAL>
__global__ void csr_agg_kernel(const int* __restrict__ row_ptr,
                               const int* __restrict__ esrc, const float* __restrict__ ecoef,
                               const float* __restrict__ h,
                               const float* __restrict__ bias, float* __restrict__ out) {
    int tid = blockIdx.x * blockDim.x + threadIdx.x;
    int stride = gridDim.x * blockDim.x;
    int lane = threadIdx.x & (D - 1);
    int node0 = tid / D;
    int nstride = stride / D;
    for (int n = node0; n < N_NODES; n += nstride) {
        int s = row_ptr[n];
        int e = row_ptr[n + 1];
        float acc = 0.0f;
        int i = s;
        for (; i + 3 < e; i += 4) {
            int s0 = esrc[i], s1 = esrc[i + 1], s2 = esrc[i + 2], s3 = esrc[i + 3];
            float c0 = ecoef[i], c1 = ecoef[i + 1], c2 = ecoef[i + 2], c3 = ecoef[i + 3];
            float h0 = h[s0 * D + lane];
            float h1 = h[s1 * D + lane];
            float h2 = h[s2 * D + lane];
            float h3 = h[s3 * D + lane];
            acc += h0 * c0 + h1 * c1 + h2 * c2 + h3 * c3;
        }
        for (; i < e; ++i) acc += h[esrc[i] * D + lane] * ecoef[i];
        if (FINAL) out[n * D + lane] = acc + bias[lane];
        else       out[n * D + lane] = acc;
    }
}

extern "C" void kernel_launch(void* const* d_in, const int* in_sizes, int n_in,
                              void* d_out, int out_size, void* d_ws, size_t ws_size,
                              hipStream_t stream) {
    const float* features = (const float*)d_in[0];
    const float* ew       = (const float*)d_in[1];
    const int*   src      = (const int*)d_in[2];
    const int*   dst      = (const int*)d_in[3];
    const float* W1       = (const float*)d_in[4];
    const float* b1       = (const float*)d_in[5];
    const float* W2       = (const float*)d_in[6];
    const float* b2       = (const float*)d_in[7];
    const float* Wp       = (const float*)d_in[8];
    const float* bp       = (const float*)d_in[9];
    float* out = (float*)d_out;

    // workspace layout (floats/ints, 4B each):
    float* ws       = (float*)d_ws;
    float* norm_src = ws;                               // N   (out-degree -> rsqrt)
    float* norm_dst = ws + N_NODES;                     // N   (in-degree  -> rsqrt)
    int*   row_ptr  = (int*)(ws + 2 * N_NODES);         // N+1
    int*   cursor   = row_ptr + (N_NODES + 1);          // N
    int*   esrc     = cursor + N_NODES;                 // E
    float* ecoef    = (float*)(esrc + N_EDGES);         // E
    float* bufA     = ecoef + N_EDGES;                  // N*64
    float* bufB     = bufA + N_NODES * 64;              // N*64

    // ---- CSR + coef build (once, reused by all 3 layers) ----
    hipMemsetAsync(norm_src, 0, 2 * N_NODES * sizeof(float), stream);
    deg_kernel<<<2048, 256, 0, stream>>>(src, dst, norm_src, norm_dst);
    scan_kernel<<<1, SCAN_T, 0, stream>>>(norm_dst, row_ptr, cursor);
    norm_kernel<<<512, 256, 0, stream>>>(norm_src, norm_dst);
    fill_kernel<<<2048, 256, 0, stream>>>(src, dst, ew, norm_src, norm_dst,
                                          cursor, esrc, ecoef);

    // ---- layer 1: bufA = A * (features @ W1)   (bias+relu deferred)
    matmul_kernel<64, false><<<1024, 256, 0, stream>>>(features, W1, nullptr, bufB);
    csr_agg_kernel<64, false><<<4096, 256, 0, stream>>>(row_ptr, esrc, ecoef, bufB, nullptr, bufA);

    // ---- layer 2: bufA = A * (relu(bufA + b1) @ W2)
    matmul_kernel<64, true><<<1024, 256, 0, stream>>>(bufA, W2, b1, bufB);
    csr_agg_kernel<64, false><<<4096, 256, 0, stream>>>(row_ptr, esrc, ecoef, bufB, nullptr, bufA);

    // ---- layer 3: out = A * (relu(bufA + b2) @ Wp) + bp
    matmul_kernel<32, true><<<1024, 256, 0, stream>>>(bufA, Wp, b2, bufB);
    csr_agg_kernel<32, true><<<4096, 256, 0, stream>>>(row_ptr, esrc, ecoef, bufB, bp, out);
}

// Round 3
// 719.980 us; speedup vs baseline: 1.8015x; 1.4009x over previous
//
#include <hip/hip_runtime.h>

#define N_NODES 100000
#define N_EDGES 1600000
#define NB_SCAN 391   // ceil(N_NODES / 256)

// ---------------- degree counting ----------------

__global__ void deg_kernel(const int* __restrict__ src, const int* __restrict__ dst,
                           float* __restrict__ deg_out, float* __restrict__ deg_in) {
    int i = blockIdx.x * blockDim.x + threadIdx.x;
    int stride = gridDim.x * blockDim.x;
    for (int e = i; e < N_EDGES; e += stride) {
        atomicAdd(&deg_out[src[e]], 1.0f);
        atomicAdd(&deg_in[dst[e]], 1.0f);
    }
}

// ---------------- 3-phase device-wide exclusive scan of in-degrees ----------------

__global__ void block_sum_kernel(const float* __restrict__ deg_in, int* __restrict__ block_sums) {
    __shared__ int sdata[256];
    int t = threadIdx.x;
    int n = blockIdx.x * 256 + t;
    int v = (n < N_NODES) ? (int)deg_in[n] : 0;
    sdata[t] = v;
    __syncthreads();
    for (int off = 128; off > 0; off >>= 1) {
        if (t < off) sdata[t] += sdata[t + off];
        __syncthreads();
    }
    if (t == 0) block_sums[blockIdx.x] = sdata[0];
}

__global__ void scan_blocks_kernel(const int* __restrict__ block_sums, int* __restrict__ block_off) {
    __shared__ int part[512];
    int t = threadIdx.x;
    int v = (t < NB_SCAN) ? block_sums[t] : 0;
    part[t] = v;
    __syncthreads();
    for (int off = 1; off < 512; off <<= 1) {
        int u = (t >= off) ? part[t - off] : 0;
        __syncthreads();
        part[t] += u;
        __syncthreads();
    }
    if (t < NB_SCAN) block_off[t] = part[t] - v;   // exclusive
}

__global__ void scatter_rowptr_kernel(const float* __restrict__ deg_in,
                                      const int* __restrict__ block_off,
                                      int* __restrict__ row_ptr, int* __restrict__ cursor) {
    __shared__ int part[256];
    int t = threadIdx.x;
    int n = blockIdx.x * 256 + t;
    int v = (n < N_NODES) ? (int)deg_in[n] : 0;
    part[t] = v;
    __syncthreads();
    for (int off = 1; off < 256; off <<= 1) {
        int u = (t >= off) ? part[t - off] : 0;
        __syncthreads();
        part[t] += u;
        __syncthreads();
    }
    int excl = part[t] - v + block_off[blockIdx.x];
    if (n < N_NODES) { row_ptr[n] = excl; cursor[n] = excl; }
    if (n == N_NODES - 1) row_ptr[N_NODES] = excl + v;
}

__global__ void norm_kernel(float* __restrict__ deg_out, float* __restrict__ deg_in) {
    int i = blockIdx.x * blockDim.x + threadIdx.x;
    int stride = gridDim.x * blockDim.x;
    for (int n = i; n < N_NODES; n += stride) {
        deg_out[n] = rsqrtf(fmaxf(deg_out[n], 1.0f));
        deg_in[n]  = rsqrtf(fmaxf(deg_in[n], 1.0f));
    }
}

// fill CSR-by-dst: packed (src, coef) per edge
__global__ void fill_kernel(const int* __restrict__ src, const int* __restrict__ dst,
                            const float* __restrict__ ew,
                            const float* __restrict__ ns, const float* __restrict__ nd,
                            int* __restrict__ cursor, int2* __restrict__ epack) {
    int i = blockIdx.x * blockDim.x + threadIdx.x;
    int stride = gridDim.x * blockDim.x;
    for (int e = i; e < N_EDGES; e += stride) {
        int s = src[e];
        int d = dst[e];
        float c = ns[s] * ew[e] * nd[d];
        int p = atomicAdd(&cursor[d], 1);
        epack[p] = make_int2(s, __float_as_int(c));
    }
}

// ---------------- dense transform: h = act(x [+b]) @ W ----------------

template <int DOUT, bool BIAS_RELU>
__global__ void matmul_kernel(const float* __restrict__ x, const float* __restrict__ W,
                              const float* __restrict__ bin, float* __restrict__ h) {
    __shared__ float Wl[64 * DOUT];
    int tid = threadIdx.x;
    for (int i = tid; i < 64 * DOUT; i += blockDim.x) Wl[i] = W[i];
    __syncthreads();

    int lane = tid & 63;
    int wid = tid >> 6;
    int wglobal = blockIdx.x * 4 + wid;
    int nwaves = gridDim.x * 4;
    int olane = lane & (DOUT - 1);

    float bv = 0.0f;
    if (BIAS_RELU) bv = bin[lane];

    for (int n = wglobal; n < N_NODES; n += nwaves) {
        float xv = x[n * 64 + lane];
        if (BIAS_RELU) xv = fmaxf(xv + bv, 0.0f);
        float acc = 0.0f;
#pragma unroll
        for (int k = 0; k < 64; ++k) {
            float xk = __shfl(xv, k);
            acc += xk * Wl[k * DOUT + olane];
        }
        if (lane < DOUT) h[n * DOUT + lane] = acc;
    }
}

// ---------------- CSR aggregation ----------------

template <int D, bool FINAL>
__global__ void csr_agg_kernel(const int* __restrict__ row_ptr,
                               const int2* __restrict__ epack,
                               const float* __restrict__ h,
                               const float* __restrict__ bias, float* __restrict__ out) {
    int tid = blockIdx.x * blockDim.x + threadIdx.x;
    int stride = gridDim.x * blockDim.x;
    int lane = threadIdx.x & (D - 1);
    int node0 = tid / D;
    int nstride = stride / D;
    for (int n = node0; n < N_NODES; n += nstride) {
        int s = row_ptr[n];
        int e = row_ptr[n + 1];
        float acc = 0.0f;
        int i = s;
        for (; i + 3 < e; i += 4) {
            int2 v0 = epack[i], v1 = epack[i + 1], v2 = epack[i + 2], v3 = epack[i + 3];
            float h0 = h[v0.x * D + lane];
            float h1 = h[v1.x * D + lane];
            float h2 = h[v2.x * D + lane];
            float h3 = h[v3.x * D + lane];
            acc += h0 * __int_as_float(v0.y) + h1 * __int_as_float(v1.y)
                 + h2 * __int_as_float(v2.y) + h3 * __int_as_float(v3.y);
        }
        for (; i < e; ++i) {
            int2 v = epack[i];
            acc += h[v.x * D + lane] * __int_as_float(v.y);
        }
        if (FINAL) out[n * D + lane] = acc + bias[lane];
        else       out[n * D + lane] = acc;
    }
}

extern "C" void kernel_launch(void* const* d_in, const int* in_sizes, int n_in,
                              void* d_out, int out_size, void* d_ws, size_t ws_size,
                              hipStream_t stream) {
    const float* features = (const float*)d_in[0];
    const float* ew       = (const float*)d_in[1];
    const int*   src      = (const int*)d_in[2];
    const int*   dst      = (const int*)d_in[3];
    const float* W1       = (const float*)d_in[4];
    const float* b1       = (const float*)d_in[5];
    const float* W2       = (const float*)d_in[6];
    const float* b2       = (const float*)d_in[7];
    const float* Wp       = (const float*)d_in[8];
    const float* bp       = (const float*)d_in[9];
    float* out = (float*)d_out;

    float* ws        = (float*)d_ws;
    float* norm_src  = ws;                              // N
    float* norm_dst  = ws + N_NODES;                    // N
    int*   row_ptr   = (int*)(ws + 2 * N_NODES);        // N+1
    int*   cursor    = row_ptr + (N_NODES + 1);         // N
    int*   block_sums= cursor + N_NODES;                // NB_SCAN
    int*   block_off = block_sums + NB_SCAN;            // NB_SCAN
    int2*  epack     = (int2*)(block_off + NB_SCAN + 1);// E int2 (8B aligned: offset parity kept even below)
    float* bufA      = (float*)(epack + N_EDGES);       // N*64
    float* bufB      = bufA + N_NODES * 64;             // N*64

    // ---- CSR + coef build (reused by all 3 layers) ----
    hipMemsetAsync(norm_src, 0, 2 * N_NODES * sizeof(float), stream);
    deg_kernel<<<2048, 256, 0, stream>>>(src, dst, norm_src, norm_dst);
    block_sum_kernel<<<NB_SCAN, 256, 0, stream>>>(norm_dst, block_sums);
    scan_blocks_kernel<<<1, 512, 0, stream>>>(block_sums, block_off);
    scatter_rowptr_kernel<<<NB_SCAN, 256, 0, stream>>>(norm_dst, block_off, row_ptr, cursor);
    norm_kernel<<<512, 256, 0, stream>>>(norm_src, norm_dst);
    fill_kernel<<<2048, 256, 0, stream>>>(src, dst, ew, norm_src, norm_dst, cursor, epack);

    // ---- layer 1: bufA = A * (features @ W1)   (bias+relu deferred)
    matmul_kernel<64, false><<<1024, 256, 0, stream>>>(features, W1, nullptr, bufB);
    csr_agg_kernel<64, false><<<4096, 256, 0, stream>>>(row_ptr, epack, bufB, nullptr, bufA);

    // ---- layer 2: bufA = A * (relu(bufA + b1) @ W2)
    matmul_kernel<64, true><<<1024, 256, 0, stream>>>(bufA, W2, b1, bufB);
    csr_agg_kernel<64, false><<<4096, 256, 0, stream>>>(row_ptr, epack, bufB, nullptr, bufA);

    // ---- layer 3: out = A * (relu(bufA + b2) @ Wp) + bp
    matmul_kernel<32, true><<<1024, 256, 0, stream>>>(bufA, Wp, b2, bufB);
    csr_agg_kernel<32, true><<<4096, 256, 0, stream>>>(row_ptr, epack, bufB, bp, out);
}

// Round 4
// 694.657 us; speedup vs baseline: 1.8672x; 1.0365x over previous
//
#include <hip/hip_runtime.h>

#define N_NODES 100000
#define N_EDGES 1600000
#define NB_SCAN 391   // ceil(N_NODES / 256)
#define R_REP 8       // histogram replicas (contention /8)

// ---------------- replicated degree counting ----------------

__global__ void deg_rep_kernel(const int* __restrict__ src, const int* __restrict__ dst,
                               unsigned int* __restrict__ degO, unsigned int* __restrict__ degI) {
    int i = blockIdx.x * blockDim.x + threadIdx.x;
    int stride = gridDim.x * blockDim.x;
    unsigned int* mO = degO + (size_t)(blockIdx.x & (R_REP - 1)) * N_NODES;
    unsigned int* mI = degI + (size_t)(blockIdx.x & (R_REP - 1)) * N_NODES;
    for (int e = i; e < N_EDGES; e += stride) {
        atomicAdd(&mO[src[e]], 1u);
        atomicAdd(&mI[dst[e]], 1u);
    }
}

// reduce replicas -> norms (rsqrt fused) + int in-degree for the scan
__global__ void reduce_norm_kernel(const unsigned int* __restrict__ degO,
                                   const unsigned int* __restrict__ degI,
                                   float* __restrict__ norm_src, float* __restrict__ norm_dst,
                                   int* __restrict__ deg_int) {
    int n = blockIdx.x * blockDim.x + threadIdx.x;
    if (n >= N_NODES) return;
    unsigned int so = 0, si = 0;
#pragma unroll
    for (int r = 0; r < R_REP; ++r) {
        so += degO[(size_t)r * N_NODES + n];
        si += degI[(size_t)r * N_NODES + n];
    }
    norm_src[n] = rsqrtf(fmaxf((float)so, 1.0f));
    norm_dst[n] = rsqrtf(fmaxf((float)si, 1.0f));
    deg_int[n] = (int)si;
}

// ---------------- 3-phase device-wide exclusive scan of in-degrees ----------------

__global__ void block_sum_kernel(const int* __restrict__ deg_in, int* __restrict__ block_sums) {
    __shared__ int sdata[256];
    int t = threadIdx.x;
    int n = blockIdx.x * 256 + t;
    int v = (n < N_NODES) ? deg_in[n] : 0;
    sdata[t] = v;
    __syncthreads();
    for (int off = 128; off > 0; off >>= 1) {
        if (t < off) sdata[t] += sdata[t + off];
        __syncthreads();
    }
    if (t == 0) block_sums[blockIdx.x] = sdata[0];
}

__global__ void scan_blocks_kernel(const int* __restrict__ block_sums, int* __restrict__ block_off) {
    __shared__ int part[512];
    int t = threadIdx.x;
    int v = (t < NB_SCAN) ? block_sums[t] : 0;
    part[t] = v;
    __syncthreads();
    for (int off = 1; off < 512; off <<= 1) {
        int u = (t >= off) ? part[t - off] : 0;
        __syncthreads();
        part[t] += u;
        __syncthreads();
    }
    if (t < NB_SCAN) block_off[t] = part[t] - v;   // exclusive
}

__global__ void scatter_rowptr_kernel(const int* __restrict__ deg_in,
                                      const int* __restrict__ block_off,
                                      int* __restrict__ row_ptr, int* __restrict__ cursor) {
    __shared__ int part[256];
    int t = threadIdx.x;
    int n = blockIdx.x * 256 + t;
    int v = (n < N_NODES) ? deg_in[n] : 0;
    part[t] = v;
    __syncthreads();
    for (int off = 1; off < 256; off <<= 1) {
        int u = (t >= off) ? part[t - off] : 0;
        __syncthreads();
        part[t] += u;
        __syncthreads();
    }
    int excl = part[t] - v + block_off[blockIdx.x];
    if (n < N_NODES) { row_ptr[n] = excl; cursor[n] = excl; }
    if (n == N_NODES - 1) row_ptr[N_NODES] = excl + v;
}

// fill CSR-by-dst: packed (src, coef) per edge
__global__ void fill_kernel(const int* __restrict__ src, const int* __restrict__ dst,
                            const float* __restrict__ ew,
                            const float* __restrict__ ns, const float* __restrict__ nd,
                            int* __restrict__ cursor, int2* __restrict__ epack) {
    int i = blockIdx.x * blockDim.x + threadIdx.x;
    int stride = gridDim.x * blockDim.x;
    for (int e = i; e < N_EDGES; e += stride) {
        int s = src[e];
        int d = dst[e];
        float c = ns[s] * ew[e] * nd[d];
        int p = atomicAdd(&cursor[d], 1);
        epack[p] = make_int2(s, __float_as_int(c));
    }
}

// ---------------- dense transform: h = act(x [+b]) @ W ----------------

template <int DOUT, bool BIAS_RELU>
__global__ void matmul_kernel(const float* __restrict__ x, const float* __restrict__ W,
                              const float* __restrict__ bin, float* __restrict__ h) {
    __shared__ float Wl[64 * DOUT];
    int tid = threadIdx.x;
    for (int i = tid; i < 64 * DOUT; i += blockDim.x) Wl[i] = W[i];
    __syncthreads();

    int lane = tid & 63;
    int wid = tid >> 6;
    int wglobal = blockIdx.x * 4 + wid;
    int nwaves = gridDim.x * 4;
    int olane = lane & (DOUT - 1);

    float bv = 0.0f;
    if (BIAS_RELU) bv = bin[lane];

    for (int n = wglobal; n < N_NODES; n += nwaves) {
        float xv = x[n * 64 + lane];
        if (BIAS_RELU) xv = fmaxf(xv + bv, 0.0f);
        float acc = 0.0f;
#pragma unroll
        for (int k = 0; k < 64; ++k) {
            float xk = __shfl(xv, k);
            acc += xk * Wl[k * DOUT + olane];
        }
        if (lane < DOUT) h[n * DOUT + lane] = acc;
    }
}

// ---------------- CSR aggregation ----------------

template <int D, bool FINAL>
__global__ void csr_agg_kernel(const int* __restrict__ row_ptr,
                               const int2* __restrict__ epack,
                               const float* __restrict__ h,
                               const float* __restrict__ bias, float* __restrict__ out) {
    int tid = blockIdx.x * blockDim.x + threadIdx.x;
    int stride = gridDim.x * blockDim.x;
    int lane = threadIdx.x & (D - 1);
    int node0 = tid / D;
    int nstride = stride / D;
    for (int n = node0; n < N_NODES; n += nstride) {
        int s = row_ptr[n];
        int e = row_ptr[n + 1];
        float acc = 0.0f;
        int i = s;
        for (; i + 3 < e; i += 4) {
            int2 v0 = epack[i], v1 = epack[i + 1], v2 = epack[i + 2], v3 = epack[i + 3];
            float h0 = h[v0.x * D + lane];
            float h1 = h[v1.x * D + lane];
            float h2 = h[v2.x * D + lane];
            float h3 = h[v3.x * D + lane];
            acc += h0 * __int_as_float(v0.y) + h1 * __int_as_float(v1.y)
                 + h2 * __int_as_float(v2.y) + h3 * __int_as_float(v3.y);
        }
        for (; i < e; ++i) {
            int2 v = epack[i];
            acc += h[v.x * D + lane] * __int_as_float(v.y);
        }
        if (FINAL) out[n * D + lane] = acc + bias[lane];
        else       out[n * D + lane] = acc;
    }
}

extern "C" void kernel_launch(void* const* d_in, const int* in_sizes, int n_in,
                              void* d_out, int out_size, void* d_ws, size_t ws_size,
                              hipStream_t stream) {
    const float* features = (const float*)d_in[0];
    const float* ew       = (const float*)d_in[1];
    const int*   src      = (const int*)d_in[2];
    const int*   dst      = (const int*)d_in[3];
    const float* W1       = (const float*)d_in[4];
    const float* b1       = (const float*)d_in[5];
    const float* W2       = (const float*)d_in[6];
    const float* b2       = (const float*)d_in[7];
    const float* Wp       = (const float*)d_in[8];
    const float* bp       = (const float*)d_in[9];
    float* out = (float*)d_out;

    // workspace layout (4B units)
    float* ws        = (float*)d_ws;
    float* norm_src  = ws;                              // N
    float* norm_dst  = ws + N_NODES;                    // N
    int*   deg_int   = (int*)(ws + 2 * N_NODES);        // N
    int*   row_ptr   = deg_int + N_NODES;               // N+1
    int*   cursor    = row_ptr + (N_NODES + 1);         // N
    int*   block_sums= cursor + N_NODES;                // NB_SCAN
    int*   block_off = block_sums + NB_SCAN;            // NB_SCAN
    int2*  epack     = (int2*)(block_off + NB_SCAN + 1);// E int2 (offset 500784, even -> 8B aligned)
    float* bufA      = (float*)(epack + N_EDGES);       // N*64
    float* bufB      = bufA + N_NODES * 64;             // N*64

    // degree replicas alias bufA (dead until agg1 writes it): 2 * R_REP * N uints = 6.4 MB
    unsigned int* degO = (unsigned int*)bufA;
    unsigned int* degI = degO + (size_t)R_REP * N_NODES;

    // ---- CSR + coef build (reused by all 3 layers) ----
    hipMemsetAsync(degO, 0, 2 * (size_t)R_REP * N_NODES * sizeof(unsigned int), stream);
    deg_rep_kernel<<<2048, 256, 0, stream>>>(src, dst, degO, degI);
    reduce_norm_kernel<<<NB_SCAN, 256, 0, stream>>>(degO, degI, norm_src, norm_dst, deg_int);
    block_sum_kernel<<<NB_SCAN, 256, 0, stream>>>(deg_int, block_sums);
    scan_blocks_kernel<<<1, 512, 0, stream>>>(block_sums, block_off);
    scatter_rowptr_kernel<<<NB_SCAN, 256, 0, stream>>>(deg_int, block_off, row_ptr, cursor);
    fill_kernel<<<2048, 256, 0, stream>>>(src, dst, ew, norm_src, norm_dst, cursor, epack);

    // ---- layer 1: bufA = A * (features @ W1)   (bias+relu deferred)
    matmul_kernel<64, false><<<1024, 256, 0, stream>>>(features, W1, nullptr, bufB);
    csr_agg_kernel<64, false><<<4096, 256, 0, stream>>>(row_ptr, epack, bufB, nullptr, bufA);

    // ---- layer 2: bufA = A * (relu(bufA + b1) @ W2)
    matmul_kernel<64, true><<<1024, 256, 0, stream>>>(bufA, W2, b1, bufB);
    csr_agg_kernel<64, false><<<4096, 256, 0, stream>>>(row_ptr, epack, bufB, nullptr, bufA);

    // ---- layer 3: out = A * (relu(bufA + b2) @ Wp) + bp
    matmul_kernel<32, true><<<1024, 256, 0, stream>>>(bufA, Wp, b2, bufB);
    csr_agg_kernel<32, true><<<4096, 256, 0, stream>>>(row_ptr, epack, bufB, bp, out);
}